// Round 12
// baseline (157.226 us; speedup 1.0000x reference)
//
#include <hip/hip_runtime.h>

#define N_IN   16384
#define N_OUT  16384
#define KSZ    9
#define CIN    32
#define COUT   32
#define BC     64
#define NCB    256         // coarse buckets = io >> 6  (64 n each)
#define CHA    4096        // bin chunk
#define ECAP_A 8192        // sivA region per coarse bucket (mean 5859)
#define ROWS   144         // 9 k * 16 n per fine slice
#define XSTR   68          // sxk row stride: %32==4 -> max 4-way on b128, 16B-aligned
#define SCAP   2048        // slist cap per fine slice (mean 1465)

// ---------------------------------------------------------------------------
// blocks 0..255: xq[in][bc] = x[bc][in]*qw[in]; block 256: wT transpose + cnt zero
__global__ void k_xq(const float* __restrict__ x, const float* __restrict__ qw,
                     float* __restrict__ xq, const float* __restrict__ w,
                     float* __restrict__ wT, int* __restrict__ gcntA) {
    const int tid = threadIdx.x;
    if (blockIdx.x == 256) {
        for (int i = tid; i < COUT * CIN * KSZ; i += 256) {
            int o = i / (CIN * KSZ);
            int r = i - o * (CIN * KSZ);
            int c = r / KSZ;
            int k = r - c * KSZ;
            wT[((k * 8 + (o >> 2)) * 32 + c) * 4 + (o & 3)] = w[i];
        }
        if (tid < NCB) gcntA[tid] = 0;
        return;
    }
    __shared__ float tile[64 * 65];
    const int in0 = blockIdx.x * 64;
#pragma unroll
    for (int i = 0; i < 16; ++i) {
        int idx = tid + i * 256;
        int bcl = idx >> 6, inl = idx & 63;
        tile[bcl * 65 + inl] = x[bcl * N_IN + in0 + inl];
    }
    __syncthreads();
#pragma unroll
    for (int i = 0; i < 16; ++i) {
        int idx = tid + i * 256;
        int inl = idx >> 6, bcl = idx & 63;
        xq[(size_t)(in0 + inl) * BC + bcl] = tile[bcl * 65 + inl] * qw[in0 + inl];
    }
}

// ---------------------------------------------------------------------------
// single-pass binning, direct-to-global scatter (no LDS staging).
// Per block: count -> reserve absolute cursors -> scatter 8B stores into this
// block's private ~128B runs (L2 write-merge). payload = (io>>4)<<22|in<<8|row.
__global__ __launch_bounds__(512) void k_binA(const float* __restrict__ vals,
        const int* __restrict__ ik, const int* __restrict__ io, const int* __restrict__ ii,
        int* __restrict__ gcntA, float2* __restrict__ sivA, int nnz) {
    __shared__ int cur[NCB];   // counts, then absolute global cursors
    const int t = threadIdx.x, c = blockIdx.x;
    if (t < NCB) cur[t] = 0;
    __syncthreads();
    const int base = c * CHA;
    const int e0   = base + t * 8;

    float vv[8]; int pk[8]; int bk[8]; bool hv[8];
    if (e0 + 8 <= nnz) {
        int4 a0 = *(const int4*)(io + e0),  a1 = *(const int4*)(io + e0 + 4);
        int4 b0 = *(const int4*)(ii + e0),  b1 = *(const int4*)(ii + e0 + 4);
        int4 k0 = *(const int4*)(ik + e0),  k1 = *(const int4*)(ik + e0 + 4);
        float4 d0 = *(const float4*)(vals + e0), d1 = *(const float4*)(vals + e0 + 4);
        int ov[8] = {a0.x, a0.y, a0.z, a0.w, a1.x, a1.y, a1.z, a1.w};
        int iv[8] = {b0.x, b0.y, b0.z, b0.w, b1.x, b1.y, b1.z, b1.w};
        int kv[8] = {k0.x, k0.y, k0.z, k0.w, k1.x, k1.y, k1.z, k1.w};
        float dv[8] = {d0.x, d0.y, d0.z, d0.w, d1.x, d1.y, d1.z, d1.w};
#pragma unroll
        for (int j = 0; j < 8; ++j) {
            hv[j] = true;
            bk[j] = ov[j] >> 6;
            pk[j] = (int)(((unsigned)(ov[j] >> 4) << 22)) | (iv[j] << 8) | (kv[j] * 16 + (ov[j] & 15));
            vv[j] = dv[j];
        }
    } else {
#pragma unroll
        for (int j = 0; j < 8; ++j) {
            int e = e0 + j;
            hv[j] = (e < nnz);
            if (hv[j]) {
                int o = io[e];
                bk[j] = o >> 6;
                pk[j] = (int)(((unsigned)(o >> 4) << 22)) | (ii[e] << 8) | (ik[e] * 16 + (o & 15));
                vv[j] = vals[e];
            } else { bk[j] = 0; pk[j] = 0; vv[j] = 0.f; }
        }
    }
#pragma unroll
    for (int j = 0; j < 8; ++j) if (hv[j]) atomicAdd(&cur[bk[j]], 1);
    __syncthreads();
    // ---- reserve: convert counts -> absolute global cursors
    if (t < NCB) {
        int cv = cur[t];
        cur[t] = t * ECAP_A + (cv ? atomicAdd(&gcntA[t], cv) : 0);
    }
    __syncthreads();
    // ---- direct scatter (stores land in this block's private runs)
#pragma unroll
    for (int j = 0; j < 8; ++j) {
        if (hv[j]) {
            int pos = atomicAdd(&cur[bk[j]], 1);
            if (pos < (bk[j] + 1) * ECAP_A)
                sivA[pos] = make_float2(vv[j], __int_as_float(pk[j]));
        }
    }
}

// ---------------------------------------------------------------------------
// fused: block = fine slice f (16 n). Two streaming passes over coarse bucket
// f>>2 (L2-hot): pass1 counts rows, pass2 scatters into sorted slist. Then
// per-wave register accumulation + two-phase einsum.
__global__ __launch_bounds__(512) void k_fused7(const float* __restrict__ xq,
        const float2* __restrict__ sivA, const int* __restrict__ gcntA,
        const float* __restrict__ wT, const float* __restrict__ bias,
        float* __restrict__ out) {
    __shared__ __align__(16) float sxk[80 * XSTR];   // 21760 B
    __shared__ float2 slist[SCAP];                   // 16384 B
    __shared__ int    rowStart[ROWS + 1];
    __shared__ int    cursor[ROWS];
    const int tid  = threadIdx.x;
    const int lane = tid & 63;
    const int wv   = __builtin_amdgcn_readfirstlane(tid >> 6);
    const unsigned f = blockIdx.x;

    if (tid < ROWS) rowStart[tid] = 0;
    __syncthreads();

    const int cb = (int)(f >> 2);
    const int mA = min(gcntA[cb], ECAP_A);
    const float2* src = sivA + (size_t)cb * ECAP_A;
    // ---- pass 1: count rows of matching entries
    for (int i = tid; i < mA; i += 512) {
        int p = __float_as_int(src[i].y);
        if (((unsigned)p >> 22) == f) atomicAdd(&rowStart[p & 0xFF], 1);
    }
    __syncthreads();
    // ---- wave-0 exclusive scan over 144 counts
    if (wv == 0) {
        int carry = 0;
#pragma unroll
        for (int i0 = 0; i0 < 192; i0 += 64) {
            int idx = i0 + lane;
            int v = (idx < ROWS) ? rowStart[idx] : 0;
            int orig = v;
#pragma unroll
            for (int off = 1; off < 64; off <<= 1) {
                int u = __shfl_up(v, off);
                if (lane >= off) v += u;
            }
            if (idx < ROWS) {
                int excl = carry + v - orig;
                rowStart[idx] = excl;
                cursor[idx]   = excl;
            }
            carry += __shfl(v, 63);
        }
        if (lane == 0) rowStart[ROWS] = carry;
    }
    __syncthreads();
    // ---- pass 2: scatter matching entries into row-sorted slist
    for (int i = tid; i < mA; i += 512) {
        float2 v = src[i];
        int p = __float_as_int(v.y);
        if (((unsigned)p >> 22) == f) {
            int pos = atomicAdd(&cursor[p & 0xFF], 1);
            if (pos < SCAP) slist[pos] = v;
        }
    }
    __syncthreads();

    const char* xqb   = (const char*)xq;
    const int   lane4 = lane * 4;
    const int   h     = lane >> 4;
    const int   nl    = lane & 15;
    float acc[4] = {0.f, 0.f, 0.f, 0.f};

#pragma unroll
    for (int ph = 0; ph < 2; ++ph) {
        const int rbase = ph ? 80 : 0;
        const int rend  = ph ? 144 : 80;
        const int nrows = rend - rbase;
        for (int i = tid; i < nrows * XSTR; i += 512) sxk[i] = 0.f;
        __syncthreads();
        // ---- per-wave row accumulation: 32-bit byte-offset gathers, 8-deep
        for (int r = rbase + wv; r < rend; r += 8) {
            const int a = min(rowStart[r], SCAP), b = min(rowStart[r + 1], SCAP);
            if (a >= b) continue;
            float acc0 = 0.f, acc1 = 0.f, acc2 = 0.f, acc3 = 0.f;
            int i = a;
            for (; i + 7 < b; i += 8) {
                float2 v0 = slist[i],     v1 = slist[i + 1], v2 = slist[i + 2], v3 = slist[i + 3];
                float2 v4 = slist[i + 4], v5 = slist[i + 5], v6 = slist[i + 6], v7 = slist[i + 7];
                acc0 += *(const float*)(xqb + ((__float_as_int(v0.y) & 0x3FFF00) + lane4)) * v0.x;
                acc1 += *(const float*)(xqb + ((__float_as_int(v1.y) & 0x3FFF00) + lane4)) * v1.x;
                acc2 += *(const float*)(xqb + ((__float_as_int(v2.y) & 0x3FFF00) + lane4)) * v2.x;
                acc3 += *(const float*)(xqb + ((__float_as_int(v3.y) & 0x3FFF00) + lane4)) * v3.x;
                acc0 += *(const float*)(xqb + ((__float_as_int(v4.y) & 0x3FFF00) + lane4)) * v4.x;
                acc1 += *(const float*)(xqb + ((__float_as_int(v5.y) & 0x3FFF00) + lane4)) * v5.x;
                acc2 += *(const float*)(xqb + ((__float_as_int(v6.y) & 0x3FFF00) + lane4)) * v6.x;
                acc3 += *(const float*)(xqb + ((__float_as_int(v7.y) & 0x3FFF00) + lane4)) * v7.x;
            }
            for (; i + 3 < b; i += 4) {
                float2 v0 = slist[i], v1 = slist[i + 1], v2 = slist[i + 2], v3 = slist[i + 3];
                acc0 += *(const float*)(xqb + ((__float_as_int(v0.y) & 0x3FFF00) + lane4)) * v0.x;
                acc1 += *(const float*)(xqb + ((__float_as_int(v1.y) & 0x3FFF00) + lane4)) * v1.x;
                acc2 += *(const float*)(xqb + ((__float_as_int(v2.y) & 0x3FFF00) + lane4)) * v2.x;
                acc3 += *(const float*)(xqb + ((__float_as_int(v3.y) & 0x3FFF00) + lane4)) * v3.x;
            }
            for (; i < b; ++i) {
                float2 v = slist[i];
                acc0 += *(const float*)(xqb + ((__float_as_int(v.y) & 0x3FFF00) + lane4)) * v.x;
            }
            sxk[(r - rbase) * XSTR + lane] = (acc0 + acc1) + (acc2 + acc3);
        }
        __syncthreads();
        // ---- partial einsum over this phase's k range
        if (lane < 32) {
            const int kbase = ph ? 5 : 0;
            const int kcnt  = ph ? 4 : 5;
            for (int kk = 0; kk < kcnt; ++kk) {
                const float* xr = &sxk[(kk * 16 + nl) * XSTR + h * 32];
                const float* wp = &wT[((kbase + kk) * 8 + wv) * 128];   // uniform -> s_load
#pragma unroll
                for (int c4 = 0; c4 < 8; ++c4) {
                    float4 xv = *(const float4*)&xr[c4 * 4];
#pragma unroll
                    for (int cc = 0; cc < 4; ++cc) {
                        float xval = (&xv.x)[cc];
#pragma unroll
                        for (int j = 0; j < 4; ++j)
                            acc[j] += xval * wp[(c4 * 4 + cc) * 4 + j];
                    }
                }
            }
        }
        __syncthreads();
    }

    if (lane < 32) {
        const int n0 = (int)f * 16;
#pragma unroll
        for (int j = 0; j < 4; ++j) {
            int o = wv * 4 + j;
            out[((size_t)h * COUT + o) * N_OUT + n0 + nl] = acc[j] + bias[o];
        }
    }
}

// ---------------------------------------------------------------------------
extern "C" void kernel_launch(void* const* d_in, const int* in_sizes, int n_in,
                              void* d_out, int out_size, void* d_ws, size_t ws_size,
                              hipStream_t stream) {
    const float* x    = (const float*)d_in[0];
    const float* qw   = (const float*)d_in[1];
    const float* vals = (const float*)d_in[2];
    const float* w    = (const float*)d_in[3];
    const float* bias = (const float*)d_in[4];
    const int*   ik   = (const int*)d_in[5];
    const int*   io   = (const int*)d_in[6];
    const int*   ii   = (const int*)d_in[7];
    const int    nnz  = in_sizes[2];
    const int    nchA = (nnz + CHA - 1) / CHA;

    char* ws = (char*)d_ws;
    float*  xq    = (float*)ws;  ws += (size_t)N_IN * BC * 4;        // 4 MB
    float2* sivA  = (float2*)ws; ws += (size_t)NCB * ECAP_A * 8;     // 16.78 MB
    int*    gcntA = (int*)ws;    ws += NCB * 4;
    float*  wT    = (float*)ws;  ws += (size_t)COUT * CIN * KSZ * 4;

    k_xq    <<<257, 256, 0, stream>>>(x, qw, xq, w, wT, gcntA);
    k_binA  <<<nchA, 512, 0, stream>>>(vals, ik, io, ii, gcntA, sivA, nnz);
    k_fused7<<<1024, 512, 0, stream>>>(xq, sivA, gcntA, wT, bias, (float*)d_out);
}

// Round 14
// 147.450 us; speedup vs baseline: 1.0663x; 1.0663x over previous
//
#include <hip/hip_runtime.h>

#define N_IN   16384
#define N_OUT  16384
#define KSZ    9
#define CIN    32
#define COUT   32
#define BC     64
#define NCB    256         // coarse buckets = io >> 6  (64 n each)
#define CHA    4096        // bin chunk
#define ECAP_A 8192        // sivA region per coarse bucket (mean 5859)
#define ROWS   144         // 9 k * 16 n per fine slice
#define XSTR   68          // sxk row stride: %32==4 -> max 4-way on b128, 16B-aligned
#define SCAP   2048        // slist cap per fine slice (mean 1465, +15 sigma)

union PrepSH {
    struct { int cnt[NCB]; int cntE[NCB]; int gbase[NCB]; int cursor[NCB];
             float2 slist[CHA]; } bin;                 // 36 KB
    struct { float tile[64 * 65]; } xqp;               // 16.6 KB
};

// ---------------------------------------------------------------------------
// k_prep: blocks [0,nchA) bin entries into 256 coarse buckets (LDS-staged,
// coalesced 128B-run flush); blocks [nchA, nchA+256) transpose x into xq;
// block nchA+256 transposes w. payload = (io>>4)<<22 | in<<8 | row.
__global__ __launch_bounds__(512) void k_prep(
        const float* __restrict__ x, const float* __restrict__ qw,
        const float* __restrict__ vals, const float* __restrict__ w,
        const int* __restrict__ ik, const int* __restrict__ io,
        const int* __restrict__ ii, float* __restrict__ xq,
        float2* __restrict__ sivA, int* __restrict__ gcntA,
        float* __restrict__ wT, int nnz, int nchA) {
    __shared__ PrepSH sh;
    const int t = threadIdx.x;
    const int bid = blockIdx.x;

    if (bid >= nchA) {
        if (bid < nchA + 256) {
            const int in0 = (bid - nchA) * 64;
#pragma unroll
            for (int i = 0; i < 8; ++i) {
                int idx = t + i * 512;
                int bcl = idx >> 6, inl = idx & 63;
                sh.xqp.tile[bcl * 65 + inl] = x[bcl * N_IN + in0 + inl];
            }
            __syncthreads();
#pragma unroll
            for (int i = 0; i < 8; ++i) {
                int idx = t + i * 512;
                int inl = idx >> 6, bcl = idx & 63;
                xq[(size_t)(in0 + inl) * BC + bcl] = sh.xqp.tile[bcl * 65 + inl] * qw[in0 + inl];
            }
        } else {
            for (int i = t; i < COUT * CIN * KSZ; i += 512) {
                int o = i / (CIN * KSZ);
                int r = i - o * (CIN * KSZ);
                int c = r / KSZ;
                int k = r - c * KSZ;
                wT[((k * 8 + (o >> 2)) * 32 + c) * 4 + (o & 3)] = w[i];
            }
        }
        return;
    }

    // ---- binning block
    if (t < NCB) sh.bin.cnt[t] = 0;
    __syncthreads();
    const int base = bid * CHA;
    const int e0   = base + t * 8;

    float vv[8]; int pk[8]; int bk[8]; bool hv[8];
    if (e0 + 8 <= nnz) {
        int4 a0 = *(const int4*)(io + e0),  a1 = *(const int4*)(io + e0 + 4);
        int4 b0 = *(const int4*)(ii + e0),  b1 = *(const int4*)(ii + e0 + 4);
        int4 k0 = *(const int4*)(ik + e0),  k1 = *(const int4*)(ik + e0 + 4);
        float4 d0 = *(const float4*)(vals + e0), d1 = *(const float4*)(vals + e0 + 4);
        int ov[8] = {a0.x, a0.y, a0.z, a0.w, a1.x, a1.y, a1.z, a1.w};
        int iv[8] = {b0.x, b0.y, b0.z, b0.w, b1.x, b1.y, b1.z, b1.w};
        int kv[8] = {k0.x, k0.y, k0.z, k0.w, k1.x, k1.y, k1.z, k1.w};
        float dv[8] = {d0.x, d0.y, d0.z, d0.w, d1.x, d1.y, d1.z, d1.w};
#pragma unroll
        for (int j = 0; j < 8; ++j) {
            hv[j] = true;
            bk[j] = ov[j] >> 6;
            pk[j] = (int)(((unsigned)(ov[j] >> 4) << 22)) | (iv[j] << 8) | (kv[j] * 16 + (ov[j] & 15));
            vv[j] = dv[j];
        }
    } else {
#pragma unroll
        for (int j = 0; j < 8; ++j) {
            int e = e0 + j;
            hv[j] = (e < nnz);
            if (hv[j]) {
                int o = io[e];
                bk[j] = o >> 6;
                pk[j] = (int)(((unsigned)(o >> 4) << 22)) | (ii[e] << 8) | (ik[e] * 16 + (o & 15));
                vv[j] = vals[e];
            } else { bk[j] = 0; pk[j] = 0; vv[j] = 0.f; }
        }
    }
#pragma unroll
    for (int j = 0; j < 8; ++j) if (hv[j]) atomicAdd(&sh.bin.cnt[bk[j]], 1);
    __syncthreads();
    if (t < NCB) {
        int cv = sh.bin.cnt[t];
        sh.bin.gbase[t] = t * ECAP_A + (cv ? atomicAdd(&gcntA[t], cv) : 0);
    }
    if (t < 64) {
        int carry = 0;
#pragma unroll
        for (int seg = 0; seg < 4; ++seg) {
            int idx = seg * 64 + t;
            int v = sh.bin.cnt[idx];
            int orig = v;
#pragma unroll
            for (int off = 1; off < 64; off <<= 1) {
                int u = __shfl_up(v, off);
                if (t >= off) v += u;
            }
            sh.bin.cntE[idx]   = carry + v - orig;
            sh.bin.cursor[idx] = carry + v - orig;
            carry += __shfl(v, 63);
        }
    }
    __syncthreads();
#pragma unroll
    for (int j = 0; j < 8; ++j) {
        if (hv[j]) {
            int pos = atomicAdd(&sh.bin.cursor[bk[j]], 1);
            sh.bin.slist[pos] = make_float2(vv[j], __int_as_float(pk[j]));
        }
    }
    __syncthreads();
    const int m = min(nnz - base, CHA);
    for (int p = t; p < m; p += 512) {
        float2 f2 = sh.bin.slist[p];
        int cb = (int)((unsigned)__float_as_int(f2.y) >> 24);
        int dest = sh.bin.gbase[cb] + (p - sh.bin.cntE[cb]);
        if (dest < (cb + 1) * ECAP_A) sivA[dest] = f2;
    }
}

// ---------------------------------------------------------------------------
// fused: block = fine slice f (16 n). Single filter pass over coarse bucket
// f>>2 into LDS tmp (aliased on sxk) + row counts; scan; LDS->LDS scatter
// (payload stripped to byte offset); per-wave register accumulation; einsum.
__global__ __launch_bounds__(512) void k_fused6(const float* __restrict__ xq,
        const float2* __restrict__ sivA, const int* __restrict__ gcntA,
        const float* __restrict__ wT, const float* __restrict__ bias,
        float* __restrict__ out) {
    __shared__ __align__(16) float sxk[80 * XSTR];   // 21760 B (>= SCAP*8 for tmp)
    __shared__ float2 slist[SCAP];                   // 16384 B
    __shared__ int    rowStart[ROWS + 1];
    __shared__ int    cursor[ROWS];
    __shared__ int    mcur;
    const int tid  = threadIdx.x;
    const int lane = tid & 63;
    const int wv   = __builtin_amdgcn_readfirstlane(tid >> 6);
    const unsigned f = blockIdx.x;

    if (tid < ROWS) rowStart[tid] = 0;
    if (tid == 0) mcur = 0;
    __syncthreads();

    const int cb = (int)(f >> 2);
    const int mA = min(gcntA[cb], ECAP_A);
    const float2* src = sivA + (size_t)cb * ECAP_A;
    float2* tmp = (float2*)sxk;
    for (int i = tid; i < mA; i += 512) {
        float2 v = src[i];
        unsigned fid = (unsigned)__float_as_int(v.y) >> 22;
        if (fid == f) {
            int pos = atomicAdd(&mcur, 1);
            if (pos < SCAP) {
                tmp[pos] = v;
                atomicAdd(&rowStart[__float_as_int(v.y) & 0xFF], 1);
            }
        }
    }
    __syncthreads();
    const int m2 = min(mcur, SCAP);
    if (wv == 0) {   // exclusive scan over 144 counts
        int carry = 0;
#pragma unroll
        for (int i0 = 0; i0 < 192; i0 += 64) {
            int idx = i0 + lane;
            int v = (idx < ROWS) ? rowStart[idx] : 0;
            int orig = v;
#pragma unroll
            for (int off = 1; off < 64; off <<= 1) {
                int u = __shfl_up(v, off);
                if (lane >= off) v += u;
            }
            if (idx < ROWS) {
                int excl = carry + v - orig;
                rowStart[idx] = excl;
                cursor[idx]   = excl;
            }
            carry += __shfl(v, 63);
        }
        if (lane == 0) rowStart[ROWS] = carry;
    }
    __syncthreads();
    // LDS->LDS scatter; strip row bits so gather needs only v_add
    for (int i = tid; i < m2; i += 512) {
        float2 v = tmp[i];
        int p = __float_as_int(v.y);
        int pos = atomicAdd(&cursor[p & 0xFF], 1);
        slist[pos] = make_float2(v.x, __int_as_float(p & 0x3FFF00));
    }
    __syncthreads();   // tmp reads complete before sxk zeroing

    const char* xqb   = (const char*)xq;
    const int   lane4 = lane * 4;
    const int   h     = lane >> 4;
    const int   nl    = lane & 15;
    float acc[4] = {0.f, 0.f, 0.f, 0.f};

#pragma unroll
    for (int ph = 0; ph < 2; ++ph) {
        const int rbase = ph ? 80 : 0;
        const int rend  = ph ? 144 : 80;
        const int nrows = rend - rbase;
        for (int i = tid; i < nrows * XSTR; i += 512) sxk[i] = 0.f;
        __syncthreads();
        for (int r = rbase + wv; r < rend; r += 8) {
            const int a = rowStart[r], b = rowStart[r + 1];
            if (a >= b) continue;
            float acc0 = 0.f, acc1 = 0.f, acc2 = 0.f, acc3 = 0.f;
            int i = a;
            for (; i + 7 < b; i += 8) {
                float2 v0 = slist[i],     v1 = slist[i + 1], v2 = slist[i + 2], v3 = slist[i + 3];
                float2 v4 = slist[i + 4], v5 = slist[i + 5], v6 = slist[i + 6], v7 = slist[i + 7];
                acc0 += *(const float*)(xqb + (__float_as_int(v0.y) + lane4)) * v0.x;
                acc1 += *(const float*)(xqb + (__float_as_int(v1.y) + lane4)) * v1.x;
                acc2 += *(const float*)(xqb + (__float_as_int(v2.y) + lane4)) * v2.x;
                acc3 += *(const float*)(xqb + (__float_as_int(v3.y) + lane4)) * v3.x;
                acc0 += *(const float*)(xqb + (__float_as_int(v4.y) + lane4)) * v4.x;
                acc1 += *(const float*)(xqb + (__float_as_int(v5.y) + lane4)) * v5.x;
                acc2 += *(const float*)(xqb + (__float_as_int(v6.y) + lane4)) * v6.x;
                acc3 += *(const float*)(xqb + (__float_as_int(v7.y) + lane4)) * v7.x;
            }
            for (; i + 3 < b; i += 4) {
                float2 v0 = slist[i], v1 = slist[i + 1], v2 = slist[i + 2], v3 = slist[i + 3];
                acc0 += *(const float*)(xqb + (__float_as_int(v0.y) + lane4)) * v0.x;
                acc1 += *(const float*)(xqb + (__float_as_int(v1.y) + lane4)) * v1.x;
                acc2 += *(const float*)(xqb + (__float_as_int(v2.y) + lane4)) * v2.x;
                acc3 += *(const float*)(xqb + (__float_as_int(v3.y) + lane4)) * v3.x;
            }
            for (; i < b; ++i) {
                float2 v = slist[i];
                acc0 += *(const float*)(xqb + (__float_as_int(v.y) + lane4)) * v.x;
            }
            sxk[(r - rbase) * XSTR + lane] = (acc0 + acc1) + (acc2 + acc3);
        }
        __syncthreads();
        if (lane < 32) {
            const int kbase = ph ? 5 : 0;
            const int kcnt  = ph ? 4 : 5;
            for (int kk = 0; kk < kcnt; ++kk) {
                const float* xr = &sxk[(kk * 16 + nl) * XSTR + h * 32];
                const float* wp = &wT[((kbase + kk) * 8 + wv) * 128];   // uniform -> s_load
#pragma unroll
                for (int c4 = 0; c4 < 8; ++c4) {
                    float4 xv = *(const float4*)&xr[c4 * 4];
#pragma unroll
                    for (int cc = 0; cc < 4; ++cc) {
                        float xval = (&xv.x)[cc];
#pragma unroll
                        for (int j = 0; j < 4; ++j)
                            acc[j] += xval * wp[(c4 * 4 + cc) * 4 + j];
                    }
                }
            }
        }
        __syncthreads();
    }

    if (lane < 32) {
        const int n0 = (int)f * 16;
#pragma unroll
        for (int j = 0; j < 4; ++j) {
            int o = wv * 4 + j;
            out[((size_t)h * COUT + o) * N_OUT + n0 + nl] = acc[j] + bias[o];
        }
    }
}

// ---------------------------------------------------------------------------
extern "C" void kernel_launch(void* const* d_in, const int* in_sizes, int n_in,
                              void* d_out, int out_size, void* d_ws, size_t ws_size,
                              hipStream_t stream) {
    const float* x    = (const float*)d_in[0];
    const float* qw   = (const float*)d_in[1];
    const float* vals = (const float*)d_in[2];
    const float* w    = (const float*)d_in[3];
    const float* bias = (const float*)d_in[4];
    const int*   ik   = (const int*)d_in[5];
    const int*   io   = (const int*)d_in[6];
    const int*   ii   = (const int*)d_in[7];
    const int    nnz  = in_sizes[2];
    const int    nchA = (nnz + CHA - 1) / CHA;

    char* ws = (char*)d_ws;
    float*  xq    = (float*)ws;  ws += (size_t)N_IN * BC * 4;        // 4 MB
    float2* sivA  = (float2*)ws; ws += (size_t)NCB * ECAP_A * 8;     // 16.78 MB
    int*    gcntA = (int*)ws;    ws += NCB * 4;
    float*  wT    = (float*)ws;  ws += (size_t)COUT * CIN * KSZ * 4;

    hipMemsetAsync(gcntA, 0, NCB * sizeof(int), stream);
    k_prep  <<<nchA + 257, 512, 0, stream>>>(x, qw, vals, w, ik, io, ii,
                                             xq, sivA, gcntA, wT, nnz, nchA);
    k_fused6<<<1024, 512, 0, stream>>>(xq, sivA, gcntA, wT, bias, (float*)d_out);
}